// Round 1
// baseline (29.941 us; speedup 1.0000x reference)
//
#include <hip/hip_runtime.h>
#include <hip/hip_bf16.h>
#include <float.h>

#define N_LOC 101
#define TAUC 0.5f
#define RAC  0.5f
#define EPSV 1e-4f

__device__ __forceinline__ float wsum64(float v) {
    #pragma unroll
    for (int off = 32; off; off >>= 1) v += __shfl_xor(v, off);
    return v;
}

// ---------------------------------------------------------------------------
// Kernel 1: w = softmax(relu(relu(x@W1+b1)@W2+b2)@W3+b3)
// grid = B/16 blocks, 256 threads. 16 rows per block.
// Thread t: row = t>>4 (0..15), owns 8 output columns j0 = (t&15)*8.
// ---------------------------------------------------------------------------
__global__ __launch_bounds__(256) void mlp_kernel(
    const float* __restrict__ x,
    const float* __restrict__ W1, const float* __restrict__ b1,
    const float* __restrict__ W2, const float* __restrict__ b2,
    const float* __restrict__ W3, const float* __restrict__ b3,
    float* __restrict__ wout)
{
    __shared__ float xs[16 * 64];
    __shared__ float h1s[16 * 132];   // stride 132: breaks bank conflicts
    __shared__ float h2s[16 * 132];
    __shared__ float lg[16 * 8];

    const int t  = threadIdx.x;
    const int r0 = blockIdx.x * 16;

    // stage x tile (16 rows x 64) -- coalesced
    for (int i = t; i < 16 * 64; i += 256) xs[i] = x[r0 * 64 + i];
    __syncthreads();

    const int row = t >> 4;
    const int j0  = (t & 15) * 8;

    // ---- h1 = relu(x @ W1 + b1), W1 is [64][128]
    {
        float acc[8];
        float4 bv0 = *reinterpret_cast<const float4*>(&b1[j0]);
        float4 bv1 = *reinterpret_cast<const float4*>(&b1[j0 + 4]);
        acc[0]=bv0.x; acc[1]=bv0.y; acc[2]=bv0.z; acc[3]=bv0.w;
        acc[4]=bv1.x; acc[5]=bv1.y; acc[6]=bv1.z; acc[7]=bv1.w;
        for (int kb = 0; kb < 64; kb += 16) {
            float hh[16];
            #pragma unroll
            for (int q = 0; q < 4; ++q) {
                float4 hv = *reinterpret_cast<const float4*>(&xs[row*64 + kb + q*4]);
                hh[q*4+0]=hv.x; hh[q*4+1]=hv.y; hh[q*4+2]=hv.z; hh[q*4+3]=hv.w;
            }
            #pragma unroll
            for (int kk = 0; kk < 16; ++kk) {
                const float* wrow = &W1[(kb + kk) * 128 + j0];
                float4 w0 = *reinterpret_cast<const float4*>(wrow);
                float4 w1 = *reinterpret_cast<const float4*>(wrow + 4);
                const float hv = hh[kk];
                acc[0] += hv * w0.x; acc[1] += hv * w0.y;
                acc[2] += hv * w0.z; acc[3] += hv * w0.w;
                acc[4] += hv * w1.x; acc[5] += hv * w1.y;
                acc[6] += hv * w1.z; acc[7] += hv * w1.w;
            }
        }
        #pragma unroll
        for (int c = 0; c < 8; ++c) h1s[row*132 + j0 + c] = fmaxf(acc[c], 0.f);
    }
    __syncthreads();

    // ---- h2 = relu(h1 @ W2 + b2), W2 is [128][128]
    {
        float acc[8];
        float4 bv0 = *reinterpret_cast<const float4*>(&b2[j0]);
        float4 bv1 = *reinterpret_cast<const float4*>(&b2[j0 + 4]);
        acc[0]=bv0.x; acc[1]=bv0.y; acc[2]=bv0.z; acc[3]=bv0.w;
        acc[4]=bv1.x; acc[5]=bv1.y; acc[6]=bv1.z; acc[7]=bv1.w;
        for (int kb = 0; kb < 128; kb += 16) {
            float hh[16];
            #pragma unroll
            for (int q = 0; q < 4; ++q) {
                float4 hv = *reinterpret_cast<const float4*>(&h1s[row*132 + kb + q*4]);
                hh[q*4+0]=hv.x; hh[q*4+1]=hv.y; hh[q*4+2]=hv.z; hh[q*4+3]=hv.w;
            }
            #pragma unroll
            for (int kk = 0; kk < 16; ++kk) {
                const float* wrow = &W2[(kb + kk) * 128 + j0];
                float4 w0 = *reinterpret_cast<const float4*>(wrow);
                float4 w1 = *reinterpret_cast<const float4*>(wrow + 4);
                const float hv = hh[kk];
                acc[0] += hv * w0.x; acc[1] += hv * w0.y;
                acc[2] += hv * w0.z; acc[3] += hv * w0.w;
                acc[4] += hv * w1.x; acc[5] += hv * w1.y;
                acc[6] += hv * w1.z; acc[7] += hv * w1.w;
            }
        }
        #pragma unroll
        for (int c = 0; c < 8; ++c) h2s[row*132 + j0 + c] = fmaxf(acc[c], 0.f);
    }
    __syncthreads();

    // ---- logits = h2 @ W3 + b3, W3 is [128][8]
    if (t < 128) {
        const int rr = t >> 3, e = t & 7;
        float a = b3[e];
        for (int k = 0; k < 128; ++k) a += h2s[rr*132 + k] * W3[k*8 + e];
        lg[rr*8 + e] = a;
    }
    __syncthreads();

    // ---- softmax over E=8, write w
    if (t < 16) {
        float v[8];
        float m = -FLT_MAX;
        #pragma unroll
        for (int e = 0; e < 8; ++e) { v[e] = lg[t*8 + e]; m = fmaxf(m, v[e]); }
        float s = 0.f;
        #pragma unroll
        for (int e = 0; e < 8; ++e) { v[e] = expf(v[e] - m); s += v[e]; }
        const float inv = 1.f / s;
        #pragma unroll
        for (int e = 0; e < 8; ++e) wout[(r0 + t)*8 + e] = v[e] * inv;
    }
}

// ---------------------------------------------------------------------------
// Kernel 2: combined_pdf = sum_e w_e * p_e; exact newsvendor solve per row.
// One wave (64 lanes) per row; lane l owns support points l and l+64.
// Closed-form objective per candidate via wave-scan prefix sums:
//   obj(k) = 2(1-RA)*[TAU*((Sp-B)-z(P-C)) + (1-TAU)*(zC-B)]
//          + 2RA*[Sq2 - 2 z Sq + z^2 Q],  z = clip(z_unc(k), lo_k, hi_k)
// ---------------------------------------------------------------------------
__global__ __launch_bounds__(256) void solve_kernel(
    const float* __restrict__ p0, const float* __restrict__ p1,
    const float* __restrict__ p2, const float* __restrict__ p3,
    const float* __restrict__ p4, const float* __restrict__ p5,
    const float* __restrict__ p6, const float* __restrict__ p7,
    const float* __restrict__ wbuf, float* __restrict__ out_pdf,
    float* __restrict__ out_z, float* __restrict__ out_err, int B)
{
    const int lane = threadIdx.x & 63;
    const int row  = blockIdx.x * 4 + (threadIdx.x >> 6);
    if (row >= B) return;
    const long base = (long)row * N_LOC;
    const float* pp[8] = { p0+base, p1+base, p2+base, p3+base,
                           p4+base, p5+base, p6+base, p7+base };
    float wv[8];
    #pragma unroll
    for (int e = 0; e < 8; ++e) wv[e] = wbuf[row*8 + e];

    const int n1 = lane, n2 = lane + 64;
    const bool v2 = (n2 < N_LOC);
    float pdf1 = 0.f, pdf2 = 0.f;
    #pragma unroll
    for (int e = 0; e < 8; ++e) {
        pdf1 += wv[e] * pp[e][n1];
        pdf2 += wv[e] * (v2 ? pp[e][n2] : 0.f);
    }
    const float s1 = n1 * 0.01f, s2 = n2 * 0.01f;

    out_pdf[base + n1] = pdf1;
    if (v2) out_pdf[base + n2] = pdf2;

    // row scalars
    const float P   = wsum64(pdf1 + pdf2);
    const float Sp  = wsum64(pdf1*s1  + pdf2*s2);
    const float Sp2 = wsum64(pdf1*s1*s1 + pdf2*s2*s2);
    const float Q   = P   + (float)N_LOC * EPSV;     // sum(p)+n*eps
    const float Sq  = Sp  + 50.5f  * EPSV;           // + eps*sum(s_i)
    const float Sq2 = Sp2 + 33.835f * EPSV;          // + eps*sum(s_i^2)

    // inclusive scans of p and p*s over both halves
    float ap = pdf1, bp = pdf2, aps = pdf1*s1, bps = pdf2*s2;
    #pragma unroll
    for (int off = 1; off < 64; off <<= 1) {
        float t0 = __shfl_up(ap,  off);
        float t1 = __shfl_up(bp,  off);
        float t2 = __shfl_up(aps, off);
        float t3 = __shfl_up(bps, off);
        if (lane >= off) { ap += t0; bp += t1; aps += t2; bps += t3; }
    }
    const float TaP  = __shfl(ap,  63);   // total of first 64 p's
    const float TaPs = __shfl(aps, 63);
    // exclusive prefixes at candidate k = n1 and k = n2
    float eC1 = __shfl_up(ap,  1); if (lane == 0) eC1 = 0.f;
    float eB1 = __shfl_up(aps, 1); if (lane == 0) eB1 = 0.f;
    float eC2 = __shfl_up(bp,  1); if (lane == 0) eC2 = 0.f;
    float eB2 = __shfl_up(bps, 1); if (lane == 0) eB2 = 0.f;
    eC2 += TaP; eB2 += TaPs;

    // candidate evaluation (closed form)
    auto evalc = [&](int k, float C, float Bv, float& zout) -> float {
        const float lo = (k == 0)   ? 0.f : (k - 1) * 0.01f;
        const float hi = (k <= 100) ? k * 0.01f : 1.f;
        float zu = (Sq + (1.f - RAC) * (TAUC * (P - C) - (1.f - TAUC) * C)
                          / (2.f * RAC)) / Q;
        float z = fminf(fmaxf(zu, lo), hi);
        float pin  = TAUC * ((Sp - Bv) - z * (P - C)) + (1.f - TAUC) * (z * C - Bv);
        float quad = Sq2 - 2.f * z * Sq + z * z * Q;
        zout = z;
        return 2.f * (1.f - RAC) * pin + 2.f * RAC * quad;
    };
    float z1 = 0.f, z2 = 0.f;
    const float o1 = evalc(n1, eC1, eB1, z1);
    const float o2 = v2 ? evalc(n2, eC2, eB2, z2) : FLT_MAX;

    float bobj; int bk; float bz;
    if (o2 < o1) { bobj = o2; bk = n2; bz = z2; }
    else         { bobj = o1; bk = n1; bz = z1; }
    // argmin reduction, first-index tiebreak (matches jnp.argmin)
    #pragma unroll
    for (int off = 32; off; off >>= 1) {
        float oo = __shfl_xor(bobj, off);
        int   ok = __shfl_xor(bk,   off);
        float oz = __shfl_xor(bz,   off);
        if (oo < bobj || (oo == bobj && ok < bk)) { bobj = oo; bk = ok; bz = oz; }
    }

    if (lane == 0) out_z[row] = bz;
    out_err[base + n1] = s1 - bz;
    if (v2) out_err[base + n2] = s2 - bz;
}

extern "C" void kernel_launch(void* const* d_in, const int* in_sizes, int n_in,
                              void* d_out, int out_size, void* d_ws, size_t ws_size,
                              hipStream_t stream)
{
    const float* x  = (const float*)d_in[0];
    const float* p[8];
    for (int e = 0; e < 8; ++e) p[e] = (const float*)d_in[1 + e];
    const float* W1 = (const float*)d_in[9];
    const float* b1 = (const float*)d_in[10];
    const float* W2 = (const float*)d_in[11];
    const float* b2 = (const float*)d_in[12];
    const float* W3 = (const float*)d_in[13];
    const float* b3 = (const float*)d_in[14];

    const int B = in_sizes[0] / 64;         // 4096
    float* wbuf    = (float*)d_ws;          // [B][8]
    float* out_pdf = (float*)d_out;         // [B][101]
    float* out_z   = out_pdf + (size_t)B * N_LOC;   // [B]
    float* out_err = out_z + B;             // [B][101]

    mlp_kernel<<<B / 16, 256, 0, stream>>>(x, W1, b1, W2, b2, W3, b3, wbuf);
    solve_kernel<<<B / 4, 256, 0, stream>>>(p[0], p[1], p[2], p[3],
                                            p[4], p[5], p[6], p[7],
                                            wbuf, out_pdf, out_z, out_err, B);
}

// Round 7
// 23.175 us; speedup vs baseline: 1.2920x; 1.2920x over previous
//
#include <hip/hip_runtime.h>
#include <hip/hip_bf16.h>
#include <float.h>

#define N_LOC 101
#define TAUC 0.5f
#define RAC  0.5f
#define EPSV 1e-4f

__device__ __forceinline__ float wsum64(float v) {
    #pragma unroll
    for (int off = 32; off; off >>= 1) v += __shfl_xor(v, off);
    return v;
}

__device__ __forceinline__ void fma4(float* acc, float s, float4 v) {
    acc[0] += s * v.x; acc[1] += s * v.y;
    acc[2] += s * v.z; acc[3] += s * v.w;
}

// ---------------------------------------------------------------------------
// Kernel 1: w = softmax(relu(relu(x@W1+b1)@W2+b2)@W3+b3)
// grid = B/16 = 256 blocks x 256 threads, 16 rows/block.
// All weights staged to LDS once per block; GEMM phases run from LDS with
// 2-row x 4-col register tiles (halves W LDS traffic vs 1-row layout).
// Thread t: row-group rg = t>>5 (rows 2rg, 2rg+1), cols j0 = (t&31)*4.
// ---------------------------------------------------------------------------
__global__ __launch_bounds__(256) void mlp_kernel(
    const float* __restrict__ x,
    const float* __restrict__ W1, const float* __restrict__ b1,
    const float* __restrict__ W2, const float* __restrict__ b2,
    const float* __restrict__ W3, const float* __restrict__ b3,
    float* __restrict__ wout)
{
    __shared__ float W1s[64 * 128];    // 32 KB
    __shared__ float W2s[128 * 128];   // 64 KB
    __shared__ float W3t[8 * 128];     // 4 KB (transposed: [e][k])
    __shared__ float xs [16 * 64];     // 4 KB
    __shared__ float h1s[16 * 132];    // stride 132 keeps float4 alignment
    __shared__ float h2s[16 * 132];
    __shared__ float lg [16 * 8];

    const int t   = threadIdx.x;
    const int r0b = blockIdx.x * 16;

    // ---- stage weights + x tile (coalesced float4 reg round-trip)
    for (int i = t * 4; i < 64 * 128; i += 1024)
        *reinterpret_cast<float4*>(&W1s[i]) = *reinterpret_cast<const float4*>(&W1[i]);
    for (int i = t * 4; i < 128 * 128; i += 1024)
        *reinterpret_cast<float4*>(&W2s[i]) = *reinterpret_cast<const float4*>(&W2[i]);
    {   // x tile: 16x64 = 1024 floats, one float4 per thread
        const int i = t * 4;
        *reinterpret_cast<float4*>(&xs[i]) = *reinterpret_cast<const float4*>(&x[r0b * 64 + i]);
    }
    {   // W3 transpose: [128][8] -> [8][128]; thread: e = t&7, kb = (t>>3)*4
        const int e = t & 7, kb = (t >> 3) * 4;
        float4 v;
        v.x = W3[(kb + 0) * 8 + e];
        v.y = W3[(kb + 1) * 8 + e];
        v.z = W3[(kb + 2) * 8 + e];
        v.w = W3[(kb + 3) * 8 + e];
        *reinterpret_cast<float4*>(&W3t[e * 128 + kb]) = v;
    }
    __syncthreads();

    const int rg = t >> 5;           // 0..7
    const int c  = t & 31;           // 0..31
    const int r0 = rg * 2, r1 = r0 + 1;
    const int j0 = c * 4;

    // ---- phase 1: h1 = relu(x @ W1 + b1), K=64
    {
        float a0[4], a1[4];
        const float4 bv = *reinterpret_cast<const float4*>(&b1[j0]);
        a0[0]=bv.x; a0[1]=bv.y; a0[2]=bv.z; a0[3]=bv.w;
        a1[0]=bv.x; a1[1]=bv.y; a1[2]=bv.z; a1[3]=bv.w;
        #pragma unroll
        for (int kb = 0; kb < 64; kb += 4) {
            const float4 ha4 = *reinterpret_cast<const float4*>(&xs[r0 * 64 + kb]);
            const float4 hb4 = *reinterpret_cast<const float4*>(&xs[r1 * 64 + kb]);
            const float ha[4] = {ha4.x, ha4.y, ha4.z, ha4.w};
            const float hb[4] = {hb4.x, hb4.y, hb4.z, hb4.w};
            #pragma unroll
            for (int q = 0; q < 4; ++q) {
                const float4 wv = *reinterpret_cast<const float4*>(&W1s[(kb + q) * 128 + j0]);
                fma4(a0, ha[q], wv);
                fma4(a1, hb[q], wv);
            }
        }
        float4 o0, o1;
        o0.x=fmaxf(a0[0],0.f); o0.y=fmaxf(a0[1],0.f); o0.z=fmaxf(a0[2],0.f); o0.w=fmaxf(a0[3],0.f);
        o1.x=fmaxf(a1[0],0.f); o1.y=fmaxf(a1[1],0.f); o1.z=fmaxf(a1[2],0.f); o1.w=fmaxf(a1[3],0.f);
        *reinterpret_cast<float4*>(&h1s[r0 * 132 + j0]) = o0;
        *reinterpret_cast<float4*>(&h1s[r1 * 132 + j0]) = o1;
    }
    __syncthreads();

    // ---- phase 2: h2 = relu(h1 @ W2 + b2), K=128
    {
        float a0[4], a1[4];
        const float4 bv = *reinterpret_cast<const float4*>(&b2[j0]);
        a0[0]=bv.x; a0[1]=bv.y; a0[2]=bv.z; a0[3]=bv.w;
        a1[0]=bv.x; a1[1]=bv.y; a1[2]=bv.z; a1[3]=bv.w;
        #pragma unroll
        for (int kb = 0; kb < 128; kb += 4) {
            const float4 ha4 = *reinterpret_cast<const float4*>(&h1s[r0 * 132 + kb]);
            const float4 hb4 = *reinterpret_cast<const float4*>(&h1s[r1 * 132 + kb]);
            const float ha[4] = {ha4.x, ha4.y, ha4.z, ha4.w};
            const float hb[4] = {hb4.x, hb4.y, hb4.z, hb4.w};
            #pragma unroll
            for (int q = 0; q < 4; ++q) {
                const float4 wv = *reinterpret_cast<const float4*>(&W2s[(kb + q) * 128 + j0]);
                fma4(a0, ha[q], wv);
                fma4(a1, hb[q], wv);
            }
        }
        float4 o0, o1;
        o0.x=fmaxf(a0[0],0.f); o0.y=fmaxf(a0[1],0.f); o0.z=fmaxf(a0[2],0.f); o0.w=fmaxf(a0[3],0.f);
        o1.x=fmaxf(a1[0],0.f); o1.y=fmaxf(a1[1],0.f); o1.z=fmaxf(a1[2],0.f); o1.w=fmaxf(a1[3],0.f);
        *reinterpret_cast<float4*>(&h2s[r0 * 132 + j0]) = o0;
        *reinterpret_cast<float4*>(&h2s[r1 * 132 + j0]) = o1;
    }
    __syncthreads();

    // ---- phase 3: logits = h2 @ W3 + b3 (16 rows x 8 experts)
    if (t < 128) {
        const int rr = t >> 3, e = t & 7;
        float s0 = 0.f, s1 = 0.f, s2 = 0.f, s3 = 0.f;
        #pragma unroll
        for (int kb = 0; kb < 128; kb += 4) {
            const float4 h = *reinterpret_cast<const float4*>(&h2s[rr * 132 + kb]);
            const float4 g = *reinterpret_cast<const float4*>(&W3t[e * 128 + kb]);
            s0 += h.x * g.x; s1 += h.y * g.y; s2 += h.z * g.z; s3 += h.w * g.w;
        }
        lg[rr * 8 + e] = b3[e] + (s0 + s1) + (s2 + s3);
    }
    __syncthreads();

    // ---- softmax over E=8, write w
    if (t < 16) {
        float v[8];
        float m = -FLT_MAX;
        #pragma unroll
        for (int e = 0; e < 8; ++e) { v[e] = lg[t * 8 + e]; m = fmaxf(m, v[e]); }
        float s = 0.f;
        #pragma unroll
        for (int e = 0; e < 8; ++e) { v[e] = expf(v[e] - m); s += v[e]; }
        const float inv = 1.f / s;
        #pragma unroll
        for (int e = 0; e < 8; ++e) wout[(r0b + t) * 8 + e] = v[e] * inv;
    }
}

// ---------------------------------------------------------------------------
// Kernel 2: combined_pdf = sum_e w_e * p_e; exact newsvendor solve per row.
// One wave per row; closed-form objective per candidate via wave-scan
// prefix sums. (Unchanged from the verified round-1 version.)
// ---------------------------------------------------------------------------
__global__ __launch_bounds__(256) void solve_kernel(
    const float* __restrict__ p0, const float* __restrict__ p1,
    const float* __restrict__ p2, const float* __restrict__ p3,
    const float* __restrict__ p4, const float* __restrict__ p5,
    const float* __restrict__ p6, const float* __restrict__ p7,
    const float* __restrict__ wbuf, float* __restrict__ out_pdf,
    float* __restrict__ out_z, float* __restrict__ out_err, int B)
{
    const int lane = threadIdx.x & 63;
    const int row  = blockIdx.x * 4 + (threadIdx.x >> 6);
    if (row >= B) return;
    const long base = (long)row * N_LOC;
    const float* pp[8] = { p0+base, p1+base, p2+base, p3+base,
                           p4+base, p5+base, p6+base, p7+base };
    float wv[8];
    #pragma unroll
    for (int e = 0; e < 8; ++e) wv[e] = wbuf[row*8 + e];

    const int n1 = lane, n2 = lane + 64;
    const bool v2 = (n2 < N_LOC);
    float pdf1 = 0.f, pdf2 = 0.f;
    #pragma unroll
    for (int e = 0; e < 8; ++e) {
        pdf1 += wv[e] * pp[e][n1];
        pdf2 += wv[e] * (v2 ? pp[e][n2] : 0.f);
    }
    const float s1 = n1 * 0.01f, s2 = n2 * 0.01f;

    out_pdf[base + n1] = pdf1;
    if (v2) out_pdf[base + n2] = pdf2;

    // row scalars
    const float P   = wsum64(pdf1 + pdf2);
    const float Sp  = wsum64(pdf1*s1  + pdf2*s2);
    const float Sp2 = wsum64(pdf1*s1*s1 + pdf2*s2*s2);
    const float Q   = P   + (float)N_LOC * EPSV;
    const float Sq  = Sp  + 50.5f  * EPSV;
    const float Sq2 = Sp2 + 33.835f * EPSV;

    // inclusive scans of p and p*s over both halves
    float ap = pdf1, bp = pdf2, aps = pdf1*s1, bps = pdf2*s2;
    #pragma unroll
    for (int off = 1; off < 64; off <<= 1) {
        float t0 = __shfl_up(ap,  off);
        float t1 = __shfl_up(bp,  off);
        float t2 = __shfl_up(aps, off);
        float t3 = __shfl_up(bps, off);
        if (lane >= off) { ap += t0; bp += t1; aps += t2; bps += t3; }
    }
    const float TaP  = __shfl(ap,  63);
    const float TaPs = __shfl(aps, 63);
    float eC1 = __shfl_up(ap,  1); if (lane == 0) eC1 = 0.f;
    float eB1 = __shfl_up(aps, 1); if (lane == 0) eB1 = 0.f;
    float eC2 = __shfl_up(bp,  1); if (lane == 0) eC2 = 0.f;
    float eB2 = __shfl_up(bps, 1); if (lane == 0) eB2 = 0.f;
    eC2 += TaP; eB2 += TaPs;

    auto evalc = [&](int k, float C, float Bv, float& zout) -> float {
        const float lo = (k == 0)   ? 0.f : (k - 1) * 0.01f;
        const float hi = (k <= 100) ? k * 0.01f : 1.f;
        float zu = (Sq + (1.f - RAC) * (TAUC * (P - C) - (1.f - TAUC) * C)
                          / (2.f * RAC)) / Q;
        float z = fminf(fmaxf(zu, lo), hi);
        float pin  = TAUC * ((Sp - Bv) - z * (P - C)) + (1.f - TAUC) * (z * C - Bv);
        float quad = Sq2 - 2.f * z * Sq + z * z * Q;
        zout = z;
        return 2.f * (1.f - RAC) * pin + 2.f * RAC * quad;
    };
    float z1 = 0.f, z2 = 0.f;
    const float o1 = evalc(n1, eC1, eB1, z1);
    const float o2 = v2 ? evalc(n2, eC2, eB2, z2) : FLT_MAX;

    float bobj; int bk; float bz;
    if (o2 < o1) { bobj = o2; bk = n2; bz = z2; }
    else         { bobj = o1; bk = n1; bz = z1; }
    #pragma unroll
    for (int off = 32; off; off >>= 1) {
        float oo = __shfl_xor(bobj, off);
        int   ok = __shfl_xor(bk,   off);
        float oz = __shfl_xor(bz,   off);
        if (oo < bobj || (oo == bobj && ok < bk)) { bobj = oo; bk = ok; bz = oz; }
    }

    if (lane == 0) out_z[row] = bz;
    out_err[base + n1] = s1 - bz;
    if (v2) out_err[base + n2] = s2 - bz;
}

extern "C" void kernel_launch(void* const* d_in, const int* in_sizes, int n_in,
                              void* d_out, int out_size, void* d_ws, size_t ws_size,
                              hipStream_t stream)
{
    const float* x  = (const float*)d_in[0];
    const float* p[8];
    for (int e = 0; e < 8; ++e) p[e] = (const float*)d_in[1 + e];
    const float* W1 = (const float*)d_in[9];
    const float* b1 = (const float*)d_in[10];
    const float* W2 = (const float*)d_in[11];
    const float* b2 = (const float*)d_in[12];
    const float* W3 = (const float*)d_in[13];
    const float* b3 = (const float*)d_in[14];

    const int B = in_sizes[0] / 64;         // 4096
    float* wbuf    = (float*)d_ws;          // [B][8]
    float* out_pdf = (float*)d_out;         // [B][101]
    float* out_z   = out_pdf + (size_t)B * N_LOC;   // [B]
    float* out_err = out_z + B;             // [B][101]

    mlp_kernel<<<B / 16, 256, 0, stream>>>(x, W1, b1, W2, b2, W3, b3, wbuf);
    solve_kernel<<<B / 4, 256, 0, stream>>>(p[0], p[1], p[2], p[3],
                                            p[4], p[5], p[6], p[7],
                                            wbuf, out_pdf, out_z, out_err, B);
}

// Round 8
// 23.079 us; speedup vs baseline: 1.2974x; 1.0042x over previous
//
#include <hip/hip_runtime.h>
#include <hip/hip_bf16.h>
#include <float.h>

#define N_LOC 101
#define TAUC 0.5f
#define RAC  0.5f
#define EPSV 1e-4f

__device__ __forceinline__ float wsum64(float v) {
    #pragma unroll
    for (int off = 32; off; off >>= 1) v += __shfl_xor(v, off);
    return v;
}

__device__ __forceinline__ void fma4(float* acc, float s, float4 v) {
    acc[0] += s * v.x; acc[1] += s * v.y;
    acc[2] += s * v.z; acc[3] += s * v.w;
}

// ---------------------------------------------------------------------------
// Fused kernel: MLP gating (16 rows/block) + newsvendor solve for those rows.
// 256 blocks x 256 threads. LDS = 50 KB -> 3 blocks/CU (12 waves/CU) so
// co-resident blocks hide staging latency; W2 staged in two 32 KB halves
// through one buffer (same total bytes, higher occupancy).
// MLP thread map: rg = t>>5 (rows 2rg,2rg+1), cols j0 = (t&31)*4, M_r=2.
// Solve: wave wv solves rows wv*4 .. wv*4+3 sequentially (round-1-verified
// closed-form per-interval quadratic + wave scans).
// ---------------------------------------------------------------------------
__global__ __launch_bounds__(256) void fused_kernel(
    const float* __restrict__ x,
    const float* __restrict__ p0, const float* __restrict__ p1,
    const float* __restrict__ p2, const float* __restrict__ p3,
    const float* __restrict__ p4, const float* __restrict__ p5,
    const float* __restrict__ p6, const float* __restrict__ p7,
    const float* __restrict__ W1, const float* __restrict__ b1,
    const float* __restrict__ W2, const float* __restrict__ b2,
    const float* __restrict__ W3, const float* __restrict__ b3,
    float* __restrict__ out_pdf, float* __restrict__ out_z,
    float* __restrict__ out_err, int B)
{
    __shared__ float buf[64 * 128];   // 32 KB: W1, then W2[0:64], W2[64:128], then W3t
    __shared__ float h1s[16 * 132];   // 8.25 KB
    __shared__ float hx [16 * 132];   // 8.25 KB: xs (16x64) in phase 1, h2s after
    __shared__ float lg [16 * 8];     // logits -> w (in place)

    const int t   = threadIdx.x;
    const int r0b = blockIdx.x * 16;

    // ---- stage W1 (32 KB) + x tile
    for (int i = t * 4; i < 64 * 128; i += 1024)
        *reinterpret_cast<float4*>(&buf[i]) = *reinterpret_cast<const float4*>(&W1[i]);
    {
        const int i = t * 4;   // 16x64 = 1024 floats
        *reinterpret_cast<float4*>(&hx[i]) = *reinterpret_cast<const float4*>(&x[r0b * 64 + i]);
    }
    __syncthreads();

    const int rg = t >> 5;           // 0..7
    const int c  = t & 31;           // 0..31
    const int r0 = rg * 2, r1 = r0 + 1;
    const int j0 = c * 4;

    // ---- phase 1: h1 = relu(x @ W1 + b1), K=64
    {
        float a0[4], a1[4];
        const float4 bv = *reinterpret_cast<const float4*>(&b1[j0]);
        a0[0]=bv.x; a0[1]=bv.y; a0[2]=bv.z; a0[3]=bv.w;
        a1[0]=bv.x; a1[1]=bv.y; a1[2]=bv.z; a1[3]=bv.w;
        #pragma unroll
        for (int kb = 0; kb < 64; kb += 4) {
            const float4 ha4 = *reinterpret_cast<const float4*>(&hx[r0 * 64 + kb]);
            const float4 hb4 = *reinterpret_cast<const float4*>(&hx[r1 * 64 + kb]);
            const float ha[4] = {ha4.x, ha4.y, ha4.z, ha4.w};
            const float hb[4] = {hb4.x, hb4.y, hb4.z, hb4.w};
            #pragma unroll
            for (int q = 0; q < 4; ++q) {
                const float4 wv = *reinterpret_cast<const float4*>(&buf[(kb + q) * 128 + j0]);
                fma4(a0, ha[q], wv);
                fma4(a1, hb[q], wv);
            }
        }
        float4 o0, o1;
        o0.x=fmaxf(a0[0],0.f); o0.y=fmaxf(a0[1],0.f); o0.z=fmaxf(a0[2],0.f); o0.w=fmaxf(a0[3],0.f);
        o1.x=fmaxf(a1[0],0.f); o1.y=fmaxf(a1[1],0.f); o1.z=fmaxf(a1[2],0.f); o1.w=fmaxf(a1[3],0.f);
        *reinterpret_cast<float4*>(&h1s[r0 * 132 + j0]) = o0;
        *reinterpret_cast<float4*>(&h1s[r1 * 132 + j0]) = o1;
    }
    __syncthreads();   // h1s ready; buf (W1) free

    // ---- phase 2: h2 = relu(h1 @ W2 + b2), K=128, staged in two 32 KB halves
    float a0[4], a1[4];
    {
        const float4 bv = *reinterpret_cast<const float4*>(&b2[j0]);
        a0[0]=bv.x; a0[1]=bv.y; a0[2]=bv.z; a0[3]=bv.w;
        a1[0]=bv.x; a1[1]=bv.y; a1[2]=bv.z; a1[3]=bv.w;
    }
    #pragma unroll
    for (int half = 0; half < 2; ++half) {
        // stage W2[half*64 : half*64+64][:]
        for (int i = t * 4; i < 64 * 128; i += 1024)
            *reinterpret_cast<float4*>(&buf[i]) =
                *reinterpret_cast<const float4*>(&W2[half * 64 * 128 + i]);
        __syncthreads();   // buf ready
        const int k0 = half * 64;
        #pragma unroll
        for (int kb = 0; kb < 64; kb += 4) {
            const float4 ha4 = *reinterpret_cast<const float4*>(&h1s[r0 * 132 + k0 + kb]);
            const float4 hb4 = *reinterpret_cast<const float4*>(&h1s[r1 * 132 + k0 + kb]);
            const float ha[4] = {ha4.x, ha4.y, ha4.z, ha4.w};
            const float hb[4] = {hb4.x, hb4.y, hb4.z, hb4.w};
            #pragma unroll
            for (int q = 0; q < 4; ++q) {
                const float4 wv = *reinterpret_cast<const float4*>(&buf[(kb + q) * 128 + j0]);
                fma4(a0, ha[q], wv);
                fma4(a1, hb[q], wv);
            }
        }
        __syncthreads();   // done reading buf before restage / next phase
    }
    {
        float4 o0, o1;
        o0.x=fmaxf(a0[0],0.f); o0.y=fmaxf(a0[1],0.f); o0.z=fmaxf(a0[2],0.f); o0.w=fmaxf(a0[3],0.f);
        o1.x=fmaxf(a1[0],0.f); o1.y=fmaxf(a1[1],0.f); o1.z=fmaxf(a1[2],0.f); o1.w=fmaxf(a1[3],0.f);
        *reinterpret_cast<float4*>(&hx[r0 * 132 + j0]) = o0;   // h2s (xs dead)
        *reinterpret_cast<float4*>(&hx[r1 * 132 + j0]) = o1;
    }
    // ---- stage W3t into buf[0:1024]: [128][8] -> [8][128]
    {
        const int e = t & 7, kb = (t >> 3) * 4;
        float4 v;
        v.x = W3[(kb + 0) * 8 + e];
        v.y = W3[(kb + 1) * 8 + e];
        v.z = W3[(kb + 2) * 8 + e];
        v.w = W3[(kb + 3) * 8 + e];
        *reinterpret_cast<float4*>(&buf[e * 128 + kb]) = v;
    }
    __syncthreads();   // h2s + W3t ready

    // ---- phase 3: logits = h2 @ W3 + b3
    if (t < 128) {
        const int rr = t >> 3, e = t & 7;
        float s0 = 0.f, s1 = 0.f, s2 = 0.f, s3 = 0.f;
        #pragma unroll
        for (int kb = 0; kb < 128; kb += 4) {
            const float4 h = *reinterpret_cast<const float4*>(&hx[rr * 132 + kb]);
            const float4 g = *reinterpret_cast<const float4*>(&buf[e * 128 + kb]);
            s0 += h.x * g.x; s1 += h.y * g.y; s2 += h.z * g.z; s3 += h.w * g.w;
        }
        lg[rr * 8 + e] = b3[e] + (s0 + s1) + (s2 + s3);
    }
    __syncthreads();

    // ---- softmax over E=8, w written back into lg
    if (t < 16) {
        float v[8];
        float m = -FLT_MAX;
        #pragma unroll
        for (int e = 0; e < 8; ++e) { v[e] = lg[t * 8 + e]; m = fmaxf(m, v[e]); }
        float s = 0.f;
        #pragma unroll
        for (int e = 0; e < 8; ++e) { v[e] = expf(v[e] - m); s += v[e]; }
        const float inv = 1.f / s;
        #pragma unroll
        for (int e = 0; e < 8; ++e) lg[t * 8 + e] = v[e] * inv;
    }
    __syncthreads();

    // ---- solve: wave wv handles rows wv*4 .. wv*4+3
    const int wv   = t >> 6;
    const int lane = t & 63;
    const int n1 = lane, n2 = lane + 64;
    const bool vld2 = (n2 < N_LOC);
    const float s1 = n1 * 0.01f, s2 = n2 * 0.01f;

    for (int rr = 0; rr < 4; ++rr) {
        const int rl  = wv * 4 + rr;          // 0..15
        const int row = r0b + rl;
        if (row >= B) break;
        const long base = (long)row * N_LOC;

        float wvv[8];
        #pragma unroll
        for (int e = 0; e < 8; ++e) wvv[e] = lg[rl * 8 + e];

        float pdf1, pdf2;
        {
            const float* pp[8] = { p0+base, p1+base, p2+base, p3+base,
                                   p4+base, p5+base, p6+base, p7+base };
            pdf1 = 0.f; pdf2 = 0.f;
            #pragma unroll
            for (int e = 0; e < 8; ++e) {
                pdf1 += wvv[e] * pp[e][n1];
                pdf2 += wvv[e] * (vld2 ? pp[e][n2] : 0.f);
            }
        }
        out_pdf[base + n1] = pdf1;
        if (vld2) out_pdf[base + n2] = pdf2;

        // row scalars
        const float P   = wsum64(pdf1 + pdf2);
        const float Sp  = wsum64(pdf1*s1  + pdf2*s2);
        const float Sp2 = wsum64(pdf1*s1*s1 + pdf2*s2*s2);
        const float Q   = P   + (float)N_LOC * EPSV;
        const float Sq  = Sp  + 50.5f  * EPSV;
        const float Sq2 = Sp2 + 33.835f * EPSV;

        // inclusive scans of p and p*s over both halves
        float ap = pdf1, bp = pdf2, aps = pdf1*s1, bps = pdf2*s2;
        #pragma unroll
        for (int off = 1; off < 64; off <<= 1) {
            float t0 = __shfl_up(ap,  off);
            float t1 = __shfl_up(bp,  off);
            float t2 = __shfl_up(aps, off);
            float t3 = __shfl_up(bps, off);
            if (lane >= off) { ap += t0; bp += t1; aps += t2; bps += t3; }
        }
        const float TaP  = __shfl(ap,  63);
        const float TaPs = __shfl(aps, 63);
        float eC1 = __shfl_up(ap,  1); if (lane == 0) eC1 = 0.f;
        float eB1 = __shfl_up(aps, 1); if (lane == 0) eB1 = 0.f;
        float eC2 = __shfl_up(bp,  1); if (lane == 0) eC2 = 0.f;
        float eB2 = __shfl_up(bps, 1); if (lane == 0) eB2 = 0.f;
        eC2 += TaP; eB2 += TaPs;

        auto evalc = [&](int k, float C, float Bv, float& zout) -> float {
            const float lo = (k == 0)   ? 0.f : (k - 1) * 0.01f;
            const float hi = (k <= 100) ? k * 0.01f : 1.f;
            float zu = (Sq + (1.f - RAC) * (TAUC * (P - C) - (1.f - TAUC) * C)
                              / (2.f * RAC)) / Q;
            float z = fminf(fmaxf(zu, lo), hi);
            float pin  = TAUC * ((Sp - Bv) - z * (P - C)) + (1.f - TAUC) * (z * C - Bv);
            float quad = Sq2 - 2.f * z * Sq + z * z * Q;
            zout = z;
            return 2.f * (1.f - RAC) * pin + 2.f * RAC * quad;
        };
        float z1 = 0.f, z2 = 0.f;
        const float o1 = evalc(n1, eC1, eB1, z1);
        const float o2 = vld2 ? evalc(n2, eC2, eB2, z2) : FLT_MAX;

        float bobj; int bk; float bz;
        if (o2 < o1) { bobj = o2; bk = n2; bz = z2; }
        else         { bobj = o1; bk = n1; bz = z1; }
        // argmin reduction, first-index tiebreak (matches jnp.argmin)
        #pragma unroll
        for (int off = 32; off; off >>= 1) {
            float oo = __shfl_xor(bobj, off);
            int   ok = __shfl_xor(bk,   off);
            float oz = __shfl_xor(bz,   off);
            if (oo < bobj || (oo == bobj && ok < bk)) { bobj = oo; bk = ok; bz = oz; }
        }

        if (lane == 0) out_z[row] = bz;
        out_err[base + n1] = s1 - bz;
        if (vld2) out_err[base + n2] = s2 - bz;
    }
}

extern "C" void kernel_launch(void* const* d_in, const int* in_sizes, int n_in,
                              void* d_out, int out_size, void* d_ws, size_t ws_size,
                              hipStream_t stream)
{
    const float* x  = (const float*)d_in[0];
    const float* p[8];
    for (int e = 0; e < 8; ++e) p[e] = (const float*)d_in[1 + e];
    const float* W1 = (const float*)d_in[9];
    const float* b1 = (const float*)d_in[10];
    const float* W2 = (const float*)d_in[11];
    const float* b2 = (const float*)d_in[12];
    const float* W3 = (const float*)d_in[13];
    const float* b3 = (const float*)d_in[14];

    const int B = in_sizes[0] / 64;         // 4096
    float* out_pdf = (float*)d_out;         // [B][101]
    float* out_z   = out_pdf + (size_t)B * N_LOC;   // [B]
    float* out_err = out_z + B;             // [B][101]

    fused_kernel<<<B / 16, 256, 0, stream>>>(
        x, p[0], p[1], p[2], p[3], p[4], p[5], p[6], p[7],
        W1, b1, W2, b2, W3, b3, out_pdf, out_z, out_err, B);
}